// Round 1
// baseline (541.928 us; speedup 1.0000x reference)
//
#include <hip/hip_runtime.h>

typedef unsigned short u16;
typedef __bf16 bf16x8 __attribute__((ext_vector_type(8)));
typedef float f32x4 __attribute__((ext_vector_type(4)));

#define B_  4
#define T_  2048
#define C_  1024
#define NH_ 16
#define D_  64
#define M_  (B_*T_)          // 8192
#define N_QKV (3*C_)         // 3072

// RNE float -> bf16 bits
__device__ __forceinline__ u16 f2bf(float f) {
  union { float f; unsigned u; } c; c.f = f;
  unsigned u = c.u;
  unsigned r = (u + 0x7fffu + ((u >> 16) & 1u)) >> 16;
  return (u16)r;
}

// ---------------- elementwise fp32 -> bf16 ----------------
__global__ __launch_bounds__(256) void conv_bf16(const float* __restrict__ in,
                                                 u16* __restrict__ out, int n) {
  int i = (blockIdx.x * 256 + threadIdx.x) * 4;
  if (i < n) {
    float4 f = *reinterpret_cast<const float4*>(in + i);
    u16 o[4] = { f2bf(f.x), f2bf(f.y), f2bf(f.z), f2bf(f.w) };
    *reinterpret_cast<uint2*>(out + i) = *reinterpret_cast<uint2*>(o);
  }
}

// ---------------- transpose fp32 [K][N] -> bf16 [N][K] ----------------
__global__ __launch_bounds__(256) void transpose_bf16(const float* __restrict__ in,
                                                      u16* __restrict__ out,
                                                      int K, int N) {
  __shared__ float tile[32][33];
  int bi = blockIdx.y;           // K/32
  int bj = blockIdx.x;           // N/32
  int tx = threadIdx.x & 31;
  int ty = threadIdx.x >> 5;     // 0..7
#pragma unroll
  for (int i = 0; i < 4; ++i) {
    int row = ty + i * 8;
    tile[row][tx] = in[(bi * 32 + row) * N + bj * 32 + tx];
  }
  __syncthreads();
#pragma unroll
  for (int i = 0; i < 4; ++i) {
    int row = ty + i * 8;
    out[(bj * 32 + row) * K + bi * 32 + tx] = f2bf(tile[tx][row]);
  }
}

// ---------------- QKV GEMM: A[M,K] x Bt[N,K] -> scatter q/k/v bf16 ----------------
// 128x128 block tile, BK=32, 4 waves (2x2), each wave 64x64 = 4x4 MFMA tiles.
__global__ __launch_bounds__(256) void gemm_qkv(const u16* __restrict__ A,
                                                const u16* __restrict__ Bt,
                                                const float* __restrict__ b_attn,
                                                const float* __restrict__ bQ,
                                                const float* __restrict__ bK,
                                                u16* __restrict__ qo,
                                                u16* __restrict__ ko,
                                                u16* __restrict__ vo) {
  const int K = C_;
  int bm = blockIdx.y, bn = blockIdx.x;
  int tid = threadIdx.x;
  int wid = tid >> 6, lane = tid & 63;
  int lm = lane & 15, lq = lane >> 4;
  int wm = (wid >> 1) * 64, wn = (wid & 1) * 64;

  __shared__ u16 As[128][40];
  __shared__ u16 Bs[128][40];

  f32x4 acc[4][4];
#pragma unroll
  for (int i = 0; i < 4; ++i)
#pragma unroll
    for (int j = 0; j < 4; ++j) acc[i][j] = (f32x4){0.f, 0.f, 0.f, 0.f};

  const u16* Ab = A + (bm * 128) * K;
  const u16* Bb = Bt + (bn * 128) * K;
  int sr = tid >> 1;
  int sc = (tid & 1) * 16;

  for (int k0 = 0; k0 < K; k0 += 32) {
    ulonglong2 va0 = *reinterpret_cast<const ulonglong2*>(Ab + sr * K + k0 + sc);
    ulonglong2 va1 = *reinterpret_cast<const ulonglong2*>(Ab + sr * K + k0 + sc + 8);
    ulonglong2 vb0 = *reinterpret_cast<const ulonglong2*>(Bb + sr * K + k0 + sc);
    ulonglong2 vb1 = *reinterpret_cast<const ulonglong2*>(Bb + sr * K + k0 + sc + 8);
    __syncthreads();
    *reinterpret_cast<ulonglong2*>(&As[sr][sc]) = va0;
    *reinterpret_cast<ulonglong2*>(&As[sr][sc + 8]) = va1;
    *reinterpret_cast<ulonglong2*>(&Bs[sr][sc]) = vb0;
    *reinterpret_cast<ulonglong2*>(&Bs[sr][sc + 8]) = vb1;
    __syncthreads();
    bf16x8 af[4], bf[4];
#pragma unroll
    for (int mt = 0; mt < 4; ++mt)
      af[mt] = *reinterpret_cast<const bf16x8*>(&As[wm + mt * 16 + lm][lq * 8]);
#pragma unroll
    for (int nt = 0; nt < 4; ++nt)
      bf[nt] = *reinterpret_cast<const bf16x8*>(&Bs[wn + nt * 16 + lm][lq * 8]);
#pragma unroll
    for (int mt = 0; mt < 4; ++mt)
#pragma unroll
      for (int nt = 0; nt < 4; ++nt)
        acc[mt][nt] = __builtin_amdgcn_mfma_f32_16x16x32_bf16(af[mt], bf[nt], acc[mt][nt], 0, 0, 0);
  }

  // epilogue: C/D layout col=lane&15, row=(lane>>4)*4+reg  [verified m89/m91]
#pragma unroll
  for (int mt = 0; mt < 4; ++mt) {
#pragma unroll
    for (int nt = 0; nt < 4; ++nt) {
#pragma unroll
      for (int r = 0; r < 4; ++r) {
        int m = bm * 128 + wm + mt * 16 + lq * 4 + r;
        int n = bn * 128 + wn + nt * 16 + lm;
        float val = acc[mt][nt][r] + b_attn[n];
        int sel = n >> 10;
        int c = n & 1023;          // h*64+d
        int h = c >> 6;
        int b = m >> 11;
        int t = m & 2047;
        int idx = (((b * NH_ + h) * T_) + t) * D_ + (c & 63);
        if (sel == 0)      qo[idx] = f2bf(val + bQ[c]);
        else if (sel == 1) ko[idx] = f2bf(val + bK[c]);
        else               vo[idx] = f2bf(val);
      }
    }
  }
}

// ---------------- Flash attention ----------------
// block = 256 threads (4 waves); one block per (b,h,q-tile of 64 rows).
// wave w owns q-rows [w*16, w*16+16).
__global__ __launch_bounds__(256) void attn_kernel(const u16* __restrict__ q,
                                                   const u16* __restrict__ k,
                                                   const u16* __restrict__ v,
                                                   u16* __restrict__ y) {
  int qt = blockIdx.x & 31;
  int bh = blockIdx.x >> 5;       // b*NH + h
  int b = bh >> 4, h = bh & 15;
  int tid = threadIdx.x, wid = tid >> 6, lane = tid & 63;
  int lm = lane & 15, lq = lane >> 4;

  __shared__ u16 Qs[64][72];
  __shared__ u16 Ks[64][72];
  __shared__ u16 Vt[64][72];      // transposed: [d][key]
  __shared__ u16 Ps[4][16][72];   // per-wave P relayout buffer

  const u16* qb = q + (bh * T_ + qt * 64) * D_;
  const u16* kb = k + bh * T_ * D_;
  const u16* vb = v + bh * T_ * D_;

  {
    int sr = tid >> 2, sc = (tid & 3) * 16;
    *reinterpret_cast<ulonglong2*>(&Qs[sr][sc]) =
        *reinterpret_cast<const ulonglong2*>(qb + sr * D_ + sc);
    *reinterpret_cast<ulonglong2*>(&Qs[sr][sc + 8]) =
        *reinterpret_cast<const ulonglong2*>(qb + sr * D_ + sc + 8);
  }
  __syncthreads();
  bf16x8 aq0 = *reinterpret_cast<const bf16x8*>(&Qs[wid * 16 + lm][0 + lq * 8]);
  bf16x8 aq1 = *reinterpret_cast<const bf16x8*>(&Qs[wid * 16 + lm][32 + lq * 8]);

  f32x4 o[4];
#pragma unroll
  for (int i = 0; i < 4; ++i) o[i] = (f32x4){0.f, 0.f, 0.f, 0.f};
  float m_prev[4], lsum[4];
#pragma unroll
  for (int r = 0; r < 4; ++r) { m_prev[r] = -1e30f; lsum[r] = 0.f; }

  const float scale = 0.125f;  // 1/sqrt(64)

  for (int kbi = 0; kbi <= qt; ++kbi) {
    __syncthreads();
    // stage K tile [key][d]
    {
      int sr = tid >> 2, sc = (tid & 3) * 16;
      const u16* kp = kb + (kbi * 64 + sr) * D_ + sc;
      *reinterpret_cast<ulonglong2*>(&Ks[sr][sc]) = *reinterpret_cast<const ulonglong2*>(kp);
      *reinterpret_cast<ulonglong2*>(&Ks[sr][sc + 8]) = *reinterpret_cast<const ulonglong2*>(kp + 8);
    }
    // stage V transposed [d][key]
#pragma unroll
    for (int it = 0; it < 2; ++it) {
      int idx = tid + it * 256;
      int r = idx >> 3, d0 = (idx & 7) * 8;
      const u16* vp = vb + (kbi * 64 + r) * D_ + d0;
      u16 tmp[8];
      *reinterpret_cast<ulonglong2*>(tmp) = *reinterpret_cast<const ulonglong2*>(vp);
#pragma unroll
      for (int j = 0; j < 8; ++j) Vt[d0 + j][r] = tmp[j];
    }
    __syncthreads();

    // S = Q K^T  (wave: 16 q-rows x 64 keys)
    f32x4 s[4];
#pragma unroll
    for (int nt = 0; nt < 4; ++nt) {
      bf16x8 kb0 = *reinterpret_cast<const bf16x8*>(&Ks[nt * 16 + lm][0 + lq * 8]);
      bf16x8 kb1 = *reinterpret_cast<const bf16x8*>(&Ks[nt * 16 + lm][32 + lq * 8]);
      f32x4 z = (f32x4){0.f, 0.f, 0.f, 0.f};
      z = __builtin_amdgcn_mfma_f32_16x16x32_bf16(aq0, kb0, z, 0, 0, 0);
      z = __builtin_amdgcn_mfma_f32_16x16x32_bf16(aq1, kb1, z, 0, 0, 0);
      s[nt] = z;
    }

    bool diag = (kbi == qt);
    // online softmax per q-row (row = lq*4+r, replicated across lanes lm)
#pragma unroll
    for (int r = 0; r < 4; ++r) {
      float mval = -1e30f;
#pragma unroll
      for (int nt = 0; nt < 4; ++nt) {
        float sv = s[nt][r] * scale;
        if (diag) {
          int qg = wid * 16 + lq * 4 + r;
          int kg = nt * 16 + lm;
          if (kg > qg) sv = -1e30f;
        }
        s[nt][r] = sv;
        mval = fmaxf(mval, sv);
      }
#pragma unroll
      for (int off = 1; off < 16; off <<= 1) mval = fmaxf(mval, __shfl_xor(mval, off));
      float mnew = fmaxf(m_prev[r], mval);
      float alpha = __expf(m_prev[r] - mnew);
      float rs = 0.f;
#pragma unroll
      for (int nt = 0; nt < 4; ++nt) {
        float p = __expf(s[nt][r] - mnew);
        s[nt][r] = p;
        rs += p;
      }
#pragma unroll
      for (int off = 1; off < 16; off <<= 1) rs += __shfl_xor(rs, off);
      lsum[r] = lsum[r] * alpha + rs;
      m_prev[r] = mnew;
#pragma unroll
      for (int nt = 0; nt < 4; ++nt) o[nt][r] *= alpha;
    }

    // P: C-layout -> A-layout via per-wave LDS (verified m120 transform)
#pragma unroll
    for (int nt = 0; nt < 4; ++nt)
#pragma unroll
      for (int r = 0; r < 4; ++r)
        Ps[wid][lq * 4 + r][nt * 16 + lm] = f2bf(s[nt][r]);

    bf16x8 p0 = *reinterpret_cast<const bf16x8*>(&Ps[wid][lm][0 + lq * 8]);
    bf16x8 p1 = *reinterpret_cast<const bf16x8*>(&Ps[wid][lm][32 + lq * 8]);
#pragma unroll
    for (int nt = 0; nt < 4; ++nt) {
      bf16x8 v0 = *reinterpret_cast<const bf16x8*>(&Vt[nt * 16 + lm][0 + lq * 8]);
      bf16x8 v1 = *reinterpret_cast<const bf16x8*>(&Vt[nt * 16 + lm][32 + lq * 8]);
      o[nt] = __builtin_amdgcn_mfma_f32_16x16x32_bf16(p0, v0, o[nt], 0, 0, 0);
      o[nt] = __builtin_amdgcn_mfma_f32_16x16x32_bf16(p1, v1, o[nt], 0, 0, 0);
    }
  }

  // write y as [B, T, NH, D] == [B,T,C]
#pragma unroll
  for (int nt = 0; nt < 4; ++nt) {
#pragma unroll
    for (int r = 0; r < 4; ++r) {
      float val = o[nt][r] / lsum[r];
      int qg = qt * 64 + wid * 16 + lq * 4 + r;
      int d = nt * 16 + lm;
      y[((b * T_ + qg) * NH_ + h) * D_ + d] = f2bf(val);
    }
  }
}

// ---------------- Proj GEMM: y[M,K] x WpT[N,K] + b_proj -> out fp32 ----------------
__global__ __launch_bounds__(256) void gemm_proj(const u16* __restrict__ A,
                                                 const u16* __restrict__ Bt,
                                                 const float* __restrict__ b_proj,
                                                 float* __restrict__ out) {
  const int K = C_, N = C_;
  int bm = blockIdx.y, bn = blockIdx.x;
  int tid = threadIdx.x;
  int wid = tid >> 6, lane = tid & 63;
  int lm = lane & 15, lq = lane >> 4;
  int wm = (wid >> 1) * 64, wn = (wid & 1) * 64;

  __shared__ u16 As[128][40];
  __shared__ u16 Bs[128][40];

  f32x4 acc[4][4];
#pragma unroll
  for (int i = 0; i < 4; ++i)
#pragma unroll
    for (int j = 0; j < 4; ++j) acc[i][j] = (f32x4){0.f, 0.f, 0.f, 0.f};

  const u16* Ab = A + (bm * 128) * K;
  const u16* Bb = Bt + (bn * 128) * K;
  int sr = tid >> 1;
  int sc = (tid & 1) * 16;

  for (int k0 = 0; k0 < K; k0 += 32) {
    ulonglong2 va0 = *reinterpret_cast<const ulonglong2*>(Ab + sr * K + k0 + sc);
    ulonglong2 va1 = *reinterpret_cast<const ulonglong2*>(Ab + sr * K + k0 + sc + 8);
    ulonglong2 vb0 = *reinterpret_cast<const ulonglong2*>(Bb + sr * K + k0 + sc);
    ulonglong2 vb1 = *reinterpret_cast<const ulonglong2*>(Bb + sr * K + k0 + sc + 8);
    __syncthreads();
    *reinterpret_cast<ulonglong2*>(&As[sr][sc]) = va0;
    *reinterpret_cast<ulonglong2*>(&As[sr][sc + 8]) = va1;
    *reinterpret_cast<ulonglong2*>(&Bs[sr][sc]) = vb0;
    *reinterpret_cast<ulonglong2*>(&Bs[sr][sc + 8]) = vb1;
    __syncthreads();
    bf16x8 af[4], bf[4];
#pragma unroll
    for (int mt = 0; mt < 4; ++mt)
      af[mt] = *reinterpret_cast<const bf16x8*>(&As[wm + mt * 16 + lm][lq * 8]);
#pragma unroll
    for (int nt = 0; nt < 4; ++nt)
      bf[nt] = *reinterpret_cast<const bf16x8*>(&Bs[wn + nt * 16 + lm][lq * 8]);
#pragma unroll
    for (int mt = 0; mt < 4; ++mt)
#pragma unroll
      for (int nt = 0; nt < 4; ++nt)
        acc[mt][nt] = __builtin_amdgcn_mfma_f32_16x16x32_bf16(af[mt], bf[nt], acc[mt][nt], 0, 0, 0);
  }

#pragma unroll
  for (int mt = 0; mt < 4; ++mt) {
#pragma unroll
    for (int nt = 0; nt < 4; ++nt) {
#pragma unroll
      for (int r = 0; r < 4; ++r) {
        int m = bm * 128 + wm + mt * 16 + lq * 4 + r;
        int n = bn * 128 + wn + nt * 16 + lm;
        out[m * N + n] = acc[mt][nt][r] + b_proj[n];
      }
    }
  }
}

extern "C" void kernel_launch(void* const* d_in, const int* in_sizes, int n_in,
                              void* d_out, int out_size, void* d_ws, size_t ws_size,
                              hipStream_t stream) {
  const float* x      = (const float*)d_in[0];
  const float* W_attn = (const float*)d_in[1];
  const float* b_attn = (const float*)d_in[2];
  const float* bQ     = (const float*)d_in[3];
  const float* bK     = (const float*)d_in[4];
  const float* W_proj = (const float*)d_in[5];
  const float* b_proj = (const float*)d_in[6];
  float* out = (float*)d_out;

  char* ws = (char*)d_ws;
  u16* xb  = (u16*)(ws);                              // [8192][1024]      16 MB
  u16* WaT = (u16*)(ws + 16777216);                   // [3072][1024]       6 MB
  u16* WpT = (u16*)(ws + 23068672);                   // [1024][1024]       2 MB
  u16* qw  = (u16*)(ws + 25165824);                   // [B,NH,T,D]        16 MB
  u16* kw  = (u16*)(ws + 41943040);                   // 16 MB
  u16* vw  = (u16*)(ws + 58720256);                   // 16 MB
  u16* yw  = (u16*)(ws + 75497472);                   // [8192][1024]      16 MB

  conv_bf16<<<M_ * C_ / (4 * 256), 256, 0, stream>>>(x, xb, M_ * C_);
  {
    dim3 g(N_QKV / 32, C_ / 32);
    transpose_bf16<<<g, 256, 0, stream>>>(W_attn, WaT, C_, N_QKV);
  }
  {
    dim3 g(C_ / 32, C_ / 32);
    transpose_bf16<<<g, 256, 0, stream>>>(W_proj, WpT, C_, C_);
  }
  {
    dim3 g(N_QKV / 128, M_ / 128);  // (24, 64)
    gemm_qkv<<<g, 256, 0, stream>>>(xb, WaT, b_attn, bQ, bK, qw, kw, vw);
  }
  attn_kernel<<<B_ * NH_ * (T_ / 64), 256, 0, stream>>>(qw, kw, vw, yw);
  {
    dim3 g(C_ / 128, M_ / 128);     // (8, 64)
    gemm_proj<<<g, 256, 0, stream>>>(yw, WpT, b_proj, out);
  }
}